// Round 6
// baseline (226.352 us; speedup 1.0000x reference)
//
#include <hip/hip_runtime.h>

typedef __bf16 bf16;
typedef __attribute__((ext_vector_type(8))) __bf16 bf16x8;
typedef __attribute__((ext_vector_type(4))) float f32x4;

union U16x8 { uint4 u; bf16 h[8]; };
union Pack4 { uint2 u2; bf16 h[4]; };

#define QSCALE 0.18033688011112042f   // log2(e)/sqrt(64)

__device__ __forceinline__ void async16(const bf16* g, bf16* l) {
    __builtin_amdgcn_global_load_lds((const __attribute__((address_space(1))) void*)g,
                                     (__attribute__((address_space(3))) void*)l, 16, 0, 0);
}

// split-K item tables: 40 items per (b,h), ordered heaviest-first
__device__ const int QT_OF[40] = {15,15,15,15,14,14,14,14,13,13,13,13,12,12,12,12,
                                  11,11,11,10,10,10,9,9,9,8,8,8,7,7,6,6,5,5,4,4,3,2,1,0};
__device__ const int CK_OF[40] = {0,1,2,3,0,1,2,3,0,1,2,3,0,1,2,3,
                                  0,1,2,0,1,2,0,1,2,0,1,2,0,1,0,1,0,1,0,1,0,0,0,0};
__device__ const int BASE_OF[16] = {39,38,37,36,34,32,30,28,25,22,19,16,12,8,4,0};

// ---------------- fp32 -> bf16 convert ----------------
__global__ void conv_f2b(const float* __restrict__ x, bf16* __restrict__ y, int n) {
    int i = (blockIdx.x * 256 + threadIdx.x) * 4;
    if (i >= n) return;
    float4 f = *(const float4*)(x + i);
    y[i + 0] = (bf16)f.x; y[i + 1] = (bf16)f.y;
    y[i + 2] = (bf16)f.z; y[i + 3] = (bf16)f.w;
}

// ---------------- batched transpose: W[K][N] fp32 -> WT[N][K] bf16, fold gains/scale ----------------
__global__ void transpose_all(const float* __restrict__ qkw, const float* __restrict__ vw,
                              const float* __restrict__ pw, bf16* __restrict__ qkvT,
                              bf16* __restrict__ pwT,
                              const float* __restrict__ vrg, const float* __restrict__ vsg,
                              const float* __restrict__ prg, const float* __restrict__ psg) {
    const int K = 1024;
    int z = blockIdx.z;
    int N = z == 0 ? 2048 : 1024;
    if ((int)blockIdx.x * 32 >= N) return;
    const float* W = z == 0 ? qkw : (z == 1 ? vw : pw);
    bf16* WT = z == 0 ? qkvT : (z == 1 ? qkvT + (size_t)2 * 1024 * 1024 : pwT);
    float g0 = z == 0 ? 1.f : (z == 1 ? vrg[0] : prg[0]);
    float g1 = z == 0 ? 0.f : (z == 1 ? vsg[0] : psg[0]);

    __shared__ float tile[32][33];
    int n0 = blockIdx.x * 32, k0 = blockIdx.y * 32;
    int tx = threadIdx.x & 31, ty = threadIdx.x >> 5;
    #pragma unroll
    for (int r = 0; r < 32; r += 8)
        tile[ty + r][tx] = W[(size_t)(k0 + ty + r) * N + n0 + tx];
    __syncthreads();
    #pragma unroll
    for (int r = 0; r < 32; r += 8) {
        int n = n0 + ty + r, k = k0 + tx;
        float v = g0 * tile[tx][ty + r] + ((n == k) ? g1 : 0.f);
        if (z == 0 && n < 1024) v *= QSCALE;   // fold softmax scale into Q weights
        WT[(size_t)n * K + k] = (bf16)v;
    }
}

// ---------------- bf16 MFMA GEMM (m97-style + swizzled DMA): C = A @ BT^T ----------------
// mode 0: fused qk+v. col<2048 -> qko (bias); col>=2048 -> vo (row-major) + vT (LDS-transposed store)
// mode 2: out fp32 = acc (gains pre-folded)
template<int BN>
__global__ __launch_bounds__(256, 2)
void gemm_bt(const bf16* __restrict__ A, const bf16* __restrict__ BT,
             int M, int N, int K, void* __restrict__ Cout, bf16* __restrict__ C2,
             bf16* __restrict__ C2T, int mode, const float* __restrict__ aux) {
    __shared__ __align__(16) bf16 smem[128 * 64 + BN * 64];
    bf16 (*As)[64] = (bf16(*)[64])smem;
    bf16 (*Bs)[64] = (bf16(*)[64])&smem[128 * 64];
    constexpr int JF = BN / 32;
    int m0 = blockIdx.y * 128, n0 = blockIdx.x * BN;
    int t = threadIdx.x, lane = t & 63, w = t >> 6;
    int wm = (w >> 1) * 64, wn = (w & 1) * (BN / 2);
    int lrow = lane & 15, lkg = lane >> 4;

    f32x4 acc[4][JF] = {};

    int gsw = ((lane & 7) ^ ((lane >> 3) & 7)) * 8;
    const bf16* Ab = A + (size_t)(m0 + w * 8 + (lane >> 3)) * K + gsw;
    const bf16* Bb = BT + (size_t)(n0 + w * 8 + (lane >> 3)) * K + gsw;

    for (int k0 = 0; k0 < K; k0 += 64) {
        #pragma unroll
        for (int p = 0; p < 4; p++)
            async16(Ab + (size_t)(p * 32) * K + k0, &As[p * 32 + w * 8][0]);
        #pragma unroll
        for (int p = 0; p < BN / 32; p++)
            async16(Bb + (size_t)(p * 32) * K + k0, &Bs[p * 32 + w * 8][0]);
        __syncthreads();
        #pragma unroll
        for (int ks = 0; ks < 2; ks++) {
            bf16x8 af[4], bfr[JF];
            int phys = (((4 * ks + lkg) ^ (lrow & 7)) << 3);
            #pragma unroll
            for (int i = 0; i < 4; i++) af[i] = *(const bf16x8*)&As[wm + i * 16 + lrow][phys];
            #pragma unroll
            for (int j = 0; j < JF; j++) bfr[j] = *(const bf16x8*)&Bs[wn + j * 16 + lrow][phys];
            #pragma unroll
            for (int i = 0; i < 4; i++)
                #pragma unroll
                for (int j = 0; j < JF; j++)
                    acc[i][j] = __builtin_amdgcn_mfma_f32_16x16x32_bf16(af[i], bfr[j], acc[i][j], 0, 0, 0);
        }
        __syncthreads();
    }

    int rgrp = (lane >> 4) * 4;
    #pragma unroll
    for (int i = 0; i < 4; i++) {
        #pragma unroll
        for (int j = 0; j < JF; j++) {
            int col = n0 + wn + j * 16 + lrow;
            int row0 = m0 + wm + i * 16 + rgrp;
            if (mode == 0) {
                if (col < 2048) {
                    float bb = aux[col];
                    if (col < 1024) bb *= QSCALE;
                    #pragma unroll
                    for (int reg = 0; reg < 4; reg++)
                        ((bf16*)Cout)[(size_t)(row0 + reg) * 2048 + col] = (bf16)(acc[i][j][reg] + bb);
                } else {
                    int c = col - 2048;
                    #pragma unroll
                    for (int reg = 0; reg < 4; reg++)
                        C2[(size_t)(row0 + reg) * 1024 + c] = (bf16)acc[i][j][reg];
                }
            } else {
                #pragma unroll
                for (int reg = 0; reg < 4; reg++)
                    ((float*)Cout)[(size_t)(row0 + reg) * N + col] = acc[i][j][reg];
            }
        }
    }

    // V-blocks: coalesced transposed store via LDS (two 64-col passes)
    if (mode == 0 && n0 >= 2048) {
        bf16* Tr = smem;          // 64 x 132 bf16, reuses staging LDS
        #pragma unroll
        for (int p = 0; p < 2; p++) {
            __syncthreads();
            if ((w & 1) == p) {
                int rbase = wm + rgrp;   // wm from this wave (0 or 64)
                #pragma unroll
                for (int i = 0; i < 4; i++) {
                    #pragma unroll
                    for (int j = 0; j < JF; j++) {
                        int c64 = j * 16 + lrow;        // 0..63 within pass
                        Pack4 p4;
                        #pragma unroll
                        for (int reg = 0; reg < 4; reg++) p4.h[reg] = (bf16)acc[i][j][reg];
                        *(uint2*)&Tr[(size_t)c64 * 132 + rbase + i * 16] = p4.u2;
                    }
                }
            }
            __syncthreads();
            int cbase = n0 - 2048 + 64 * p;
            #pragma unroll
            for (int it = 0; it < 8; it++) {
                int u = it * 256 + t;
                int c = u >> 5, rg4 = (u & 31) * 4;
                *(uint2*)&C2T[(size_t)(cbase + c) * 4096 + m0 + rg4] = *(const uint2*)&Tr[(size_t)c * 132 + rg4];
            }
        }
    }
}

// ---------------- flash split-K, fixed-base softmax (no running max) ----------------
__global__ __launch_bounds__(256, 3)
void flash_split(const bf16* __restrict__ qk, const bf16* __restrict__ vT,
                 bf16* __restrict__ Opart, float* __restrict__ lbuf,
                 int S, int E, int H) {
    __shared__ __align__(16) bf16 Ks[2][64][64];   // swizzled DMA: [key][d-group ^ (key&7)]
    __shared__ __align__(16) bf16 Vt[2][64][64];   // swizzled DMA: [d][key-group ^ (d&7)]
    __shared__ __align__(16) bf16 Ps[4][32][72];   // per-wave: [qrow-local][key]

    int item = blockIdx.x, bh = blockIdx.y;
    int qt = QT_OF[item], ck = CK_OF[item];
    int b = bh >> 4, h = bh & 15;
    int q0 = qt * 128;
    int ktstart = ck * 8;
    int nloc = min(8, 2 * (qt + 1) - ktstart);
    int t = threadIdx.x, lane = t & 63, w = t >> 6;
    int lrow = lane & 15, lkg = lane >> 4;
    const int ld = 2 * E;

    const bf16* Qg  = qk + (size_t)(b * S + q0) * ld + h * 64;
    const bf16* Kg0 = qk + (size_t)(b * S) * ld + E + h * 64;
    const bf16* Vg0 = vT + (size_t)(h * 64) * 4096 + b * 2048;

    bf16x8 qf[2][2];
    #pragma unroll
    for (int qg = 0; qg < 2; qg++)
        #pragma unroll
        for (int ks = 0; ks < 2; ks++)
            qf[qg][ks] = *(const bf16x8*)&Qg[(size_t)(32 * w + 16 * qg + lrow) * ld + ks * 32 + lkg * 8];

    f32x4 oacc[4][2] = {};
    float lrun[2] = {0.f, 0.f};

    auto stage = [&](int buf, int kt) {
        int k0 = kt * 64;
        int g = (lane & 7) ^ ((lane >> 3) & 7);
        #pragma unroll
        for (int p = 0; p < 2; p++) {
            int row = w * 8 + p * 32 + (lane >> 3);
            async16(Kg0 + (size_t)(k0 + row) * ld + g * 8, &Ks[buf][row][(lane & 7) * 8]);
            async16(Vg0 + (size_t)row * 4096 + k0 + g * 8, &Vt[buf][row][(lane & 7) * 8]);
        }
    };

    stage(0, ktstart);
    for (int kl = 0; kl < nloc; kl++) {
        int buf = kl & 1;
        int k0 = (ktstart + kl) * 64;
        __syncthreads();
        if (kl + 1 < nloc) stage(1 - buf, ktstart + kl + 1);

        bool skip0 = (k0 > q0 + 32 * w + 15);
        bool skip1 = (k0 > q0 + 32 * w + 31);
        if (skip0 && skip1) continue;

        f32x4 sacc[2][4] = {};
        #pragma unroll
        for (int ks = 0; ks < 2; ks++) {
            bf16x8 ak[4];
            int phys = (((4 * ks + lkg) ^ (lrow & 7)) << 3);
            #pragma unroll
            for (int kf = 0; kf < 4; kf++)
                ak[kf] = *(const bf16x8*)&Ks[buf][16 * kf + lrow][phys];
            #pragma unroll
            for (int kf = 0; kf < 4; kf++)
                sacc[0][kf] = __builtin_amdgcn_mfma_f32_16x16x32_bf16(ak[kf], qf[0][ks], sacc[0][kf], 0, 0, 0);
            if (!skip1)
                #pragma unroll
                for (int kf = 0; kf < 4; kf++)
                    sacc[1][kf] = __builtin_amdgcn_mfma_f32_16x16x32_bf16(ak[kf], qf[1][ks], sacc[1][kf], 0, 0, 0);
        }

        #pragma unroll
        for (int qg = 0; qg < 2; qg++) {
            if ((qg == 0 && skip0) || (qg == 1 && skip1)) continue;
            int kmin = q0 + 32 * w + 16 * qg;
            bool diag = (k0 + 63 > kmin);
            int qrow = kmin + lrow;
            float rsum = 0.f;
            #pragma unroll
            for (int kf = 0; kf < 4; kf++) {
                Pack4 p4;
                #pragma unroll
                for (int r = 0; r < 4; r++) {
                    float sv = sacc[qg][kf][r];
                    if (diag && (k0 + 16 * kf + 4 * lkg + r > qrow)) sv = -1e30f;
                    float p = exp2f(sv);
                    rsum += p;
                    p4.h[r] = (bf16)p;
                }
                *(uint2*)&Ps[w][16 * qg + lrow][16 * kf + 4 * lkg] = p4.u2;
            }
            lrun[qg] += rsum;
        }

        #pragma unroll
        for (int ks = 0; ks < 2; ks++) {
            bf16x8 av[4];
            int phys = (((4 * ks + lkg) ^ (lrow & 7)) << 3);
            #pragma unroll
            for (int df = 0; df < 4; df++)
                av[df] = *(const bf16x8*)&Vt[buf][16 * df + lrow][phys];
            #pragma unroll
            for (int qg = 0; qg < 2; qg++) {
                if ((qg == 0 && skip0) || (qg == 1 && skip1)) continue;
                bf16x8 bp = *(const bf16x8*)&Ps[w][16 * qg + lrow][ks * 32 + lkg * 8];
                #pragma unroll
                for (int df = 0; df < 4; df++)
                    oacc[df][qg] = __builtin_amdgcn_mfma_f32_16x16x32_bf16(av[df], bp, oacc[df][qg], 0, 0, 0);
            }
        }
    }

    size_t ibase = (size_t)(bh * 40 + item) * 128;
    #pragma unroll
    for (int qg = 0; qg < 2; qg++) {
        #pragma unroll
        for (int df = 0; df < 4; df++) {
            Pack4 p4;
            #pragma unroll
            for (int r = 0; r < 4; r++) p4.h[r] = (bf16)oacc[df][qg][r];
            *(uint2*)&Ps[w][16 * qg + lrow][16 * df + 4 * lkg] = p4.u2;
        }
        float l = lrun[qg];
        l += __shfl_xor(l, 16, 64);
        l += __shfl_xor(l, 32, 64);
        if (lkg == 0) lbuf[ibase + w * 32 + qg * 16 + lrow] = l;
    }
    int r_l = lane >> 1, half = lane & 1;
    bf16* orow = Opart + (ibase + w * 32 + r_l) * 64 + 32 * half;
    #pragma unroll
    for (int c = 0; c < 4; c++)
        *(uint4*)&orow[8 * c] = *(const uint4*)&Ps[w][r_l][32 * half + 8 * c];
}

// ---------------- fused merge + combine: per (qt, bh) block ----------------
// phase A: merge partials -> normalized O in LDS. phase B: ctx = gr*O + gs*v - gc*prefix_mean(v)
__global__ void merge_combine(const bf16* __restrict__ Opart, const float* __restrict__ lbuf,
                              const bf16* __restrict__ v, const float* __restrict__ csum,
                              const float* __restrict__ gr, const float* __restrict__ gs,
                              const float* __restrict__ gc, bf16* __restrict__ ctx) {
    const int S = 2048, E = 1024;
    int qt = blockIdx.x, bh = blockIdx.y;
    int b = bh >> 4, h = bh & 15;
    int nc = (qt >> 2) + 1, base = BASE_OF[qt];
    int q0 = qt * 128;
    int t = threadIdx.x;

    __shared__ float osm[128][65];

    // phase A
    {
        int r = t >> 1, dh = (t & 1) * 32;
        float L = 0.f;
        for (int c = 0; c < nc; c++)
            L += lbuf[(size_t)(bh * 40 + base + c) * 128 + r];
        float inv = 1.f / L;
        float o[32] = {};
        for (int c = 0; c < nc; c++) {
            const bf16* src = Opart + ((size_t)(bh * 40 + base + c) * 128 + r) * 64 + dh;
            #pragma unroll
            for (int g = 0; g < 4; g++) {
                U16x8 u; u.u = *(const uint4*)&src[g * 8];
                #pragma unroll
                for (int j = 0; j < 8; j++) o[g * 8 + j] += (float)u.h[j];
            }
        }
        #pragma unroll
        for (int j = 0; j < 32; j++) osm[r][dh + j] = o[j] * inv;
    }
    __syncthreads();

    // phase B: 128 active threads, one per (column, chunk-of-64-rows)
    if (t < 128) {
        int c = t & 63, ckk = t >> 6;             // ckk in {0,1}
        int col = h * 64 + c;
        float grh = gr[h], gsh = gs[h], gch = gc[h];
        int chunk = (q0 >> 6) + ckk;
        float run = csum[((size_t)b * 32 + chunk) * E + col];
        const bf16* vp = v + ((size_t)b * S + chunk * 64) * E + col;
        bf16* cp = ctx + ((size_t)b * S + chunk * 64) * E + col;
        for (int i = 0; i < 64; i++) {
            int row = chunk * 64 + i;
            float vv = (float)vp[(size_t)i * E];
            run += vv;
            float pm = run / (float)(row + 1);
            cp[(size_t)i * E] = (bf16)(grh * osm[ckk * 64 + i][c] + gsh * vv - gch * pm);
        }
    }
}

// ---------------- prefix-sum phases ----------------
__global__ void chunk_sum(const bf16* __restrict__ v, float* __restrict__ csum) {
    const int S = 2048, E = 1024;
    int colblk = blockIdx.x & 3, chunk = (blockIdx.x >> 2) & 31, b = blockIdx.x >> 7;
    int col = colblk * 256 + threadIdx.x;
    const bf16* p = v + ((size_t)b * S + chunk * 64) * E + col;
    float s = 0.f;
    #pragma unroll 4
    for (int i = 0; i < 64; i++) s += (float)p[(size_t)i * E];
    csum[((size_t)b * 32 + chunk) * E + col] = s;
}
__global__ void chunk_scan(float* __restrict__ csum) {
    const int E = 1024;
    int b = blockIdx.x >> 2;
    int col = (blockIdx.x & 3) * 256 + threadIdx.x;
    float x[32];
    #pragma unroll
    for (int c = 0; c < 32; c++)
        x[c] = csum[((size_t)b * 32 + c) * E + col];
    float run = 0.f;
    #pragma unroll
    for (int c = 0; c < 32; c++) {
        float cur = x[c];
        csum[((size_t)b * 32 + c) * E + col] = run;
        run += cur;
    }
}

extern "C" void kernel_launch(void* const* d_in, const int* in_sizes, int n_in,
                              void* d_out, int out_size, void* d_ws, size_t ws_size,
                              hipStream_t stream) {
    const float* hs  = (const float*)d_in[0];
    const float* qkw = (const float*)d_in[1];
    const float* qkb = (const float*)d_in[2];
    const float* vw  = (const float*)d_in[3];
    const float* vrg = (const float*)d_in[4];
    const float* vsg = (const float*)d_in[5];
    const float* pw  = (const float*)d_in[6];
    const float* prg = (const float*)d_in[7];
    const float* psg = (const float*)d_in[8];
    const float* amr = (const float*)d_in[9];
    const float* ams = (const float*)d_in[10];
    const float* amc = (const float*)d_in[11];
    float* out = (float*)d_out;

    const int B = 2, S = 2048, E = 1024, H = 16, M = B * S;
    char* ws = (char*)d_ws;
    size_t off = 0;
    auto alloc = [&](size_t bytes) { void* p = ws + off; off += (bytes + 255) & ~255ull; return p; };
    bf16* hsb   = (bf16*)alloc((size_t)M * E * 2);
    bf16* qkvT  = (bf16*)alloc((size_t)3 * E * E * 2);
    bf16* pwT   = (bf16*)alloc((size_t)E * E * 2);
    bf16* qko   = (bf16*)alloc((size_t)M * 2 * E * 2);
    bf16* vo    = (bf16*)alloc((size_t)M * E * 2);
    bf16* vT    = (bf16*)alloc((size_t)E * M * 2);
    float* csum = (float*)alloc((size_t)B * 32 * E * 4);
    bf16* ctxb  = (bf16*)alloc((size_t)M * E * 2);
    bf16* Opart = (bf16*)alloc((size_t)32 * 40 * 128 * 64 * 2);
    float* lbuf = (float*)alloc((size_t)32 * 40 * 128 * 4);

    conv_f2b<<<M * E / 4 / 256, 256, 0, stream>>>(hs, hsb, M * E);
    transpose_all<<<dim3(64, 32, 3), 256, 0, stream>>>(qkw, vw, pw, qkvT, pwT, vrg, vsg, prg, psg);

    gemm_bt<128><<<dim3(3 * E / 128, M / 128), 256, 0, stream>>>(
        hsb, qkvT, M, 3 * E, E, qko, vo, vT, 0, qkb);

    chunk_sum<<<256, 256, 0, stream>>>(vo, csum);
    chunk_scan<<<8, 256, 0, stream>>>(csum);
    flash_split<<<dim3(40, 32), 256, 0, stream>>>(qko, vT, Opart, lbuf, S, E, H);
    merge_combine<<<dim3(16, 32), 256, 0, stream>>>(Opart, lbuf, vo, csum, amr, ams, amc, ctxb);

    gemm_bt<64><<<dim3(E / 64, M / 128), 256, 0, stream>>>(
        ctxb, pwT, M, E, E, out, nullptr, nullptr, 2, nullptr);
}

// Round 7
// 216.505 us; speedup vs baseline: 1.0455x; 1.0455x over previous
//
#include <hip/hip_runtime.h>

typedef __bf16 bf16;
typedef __attribute__((ext_vector_type(8))) __bf16 bf16x8;
typedef __attribute__((ext_vector_type(4))) float f32x4;

union U16x8 { uint4 u; bf16 h[8]; };
union Pack4 { uint2 u2; bf16 h[4]; };

#define QSCALE 0.18033688011112042f   // log2(e)/sqrt(64)

__device__ __forceinline__ void async16(const bf16* g, bf16* l) {
    __builtin_amdgcn_global_load_lds((const __attribute__((address_space(1))) void*)g,
                                     (__attribute__((address_space(3))) void*)l, 16, 0, 0);
}

// split-K item tables: 40 items per (b,h), ordered heaviest-first
__device__ const int QT_OF[40] = {15,15,15,15,14,14,14,14,13,13,13,13,12,12,12,12,
                                  11,11,11,10,10,10,9,9,9,8,8,8,7,7,6,6,5,5,4,4,3,2,1,0};
__device__ const int CK_OF[40] = {0,1,2,3,0,1,2,3,0,1,2,3,0,1,2,3,
                                  0,1,2,0,1,2,0,1,2,0,1,2,0,1,0,1,0,1,0,1,0,0,0,0};
__device__ const int BASE_OF[16] = {39,38,37,36,34,32,30,28,25,22,19,16,12,8,4,0};

// ---------------- prep: fp32->bf16 convert + 3 weight transposes, one launch ----------------
// blocks 0..4095: conv (4M elems / 4 / 256); 4096..6143: qkw T; 6144..7167: vw T; 7168..8191: pw T
__global__ void prep(const float* __restrict__ hs, bf16* __restrict__ hsb,
                     const float* __restrict__ qkw, const float* __restrict__ vw,
                     const float* __restrict__ pw, bf16* __restrict__ qkvT,
                     bf16* __restrict__ pwT,
                     const float* __restrict__ vrg, const float* __restrict__ vsg,
                     const float* __restrict__ prg, const float* __restrict__ psg) {
    const int K = 1024;
    int bx = blockIdx.x;
    if (bx < 4096) {
        int i = (bx * 256 + threadIdx.x) * 4;
        float4 f = *(const float4*)(hs + i);
        hsb[i + 0] = (bf16)f.x; hsb[i + 1] = (bf16)f.y;
        hsb[i + 2] = (bf16)f.z; hsb[i + 3] = (bf16)f.w;
        return;
    }
    int r = bx - 4096;
    int z = r < 2048 ? 0 : (r < 3072 ? 1 : 2);
    int q = z == 0 ? r : (z == 1 ? r - 2048 : r - 3072);
    int ntiles = z == 0 ? 64 : 32;
    int N = z == 0 ? 2048 : 1024;
    const float* W = z == 0 ? qkw : (z == 1 ? vw : pw);
    bf16* WT = z == 0 ? qkvT : (z == 1 ? qkvT + (size_t)2 * 1024 * 1024 : pwT);
    float g0 = z == 0 ? 1.f : (z == 1 ? vrg[0] : prg[0]);
    float g1 = z == 0 ? 0.f : (z == 1 ? vsg[0] : psg[0]);

    __shared__ float tile[32][33];
    int n0 = (q % ntiles) * 32, k0 = (q / ntiles) * 32;
    int tx = threadIdx.x & 31, ty = threadIdx.x >> 5;
    #pragma unroll
    for (int rr = 0; rr < 32; rr += 8)
        tile[ty + rr][tx] = W[(size_t)(k0 + ty + rr) * N + n0 + tx];
    __syncthreads();
    #pragma unroll
    for (int rr = 0; rr < 32; rr += 8) {
        int n = n0 + ty + rr, k = k0 + tx;
        float v = g0 * tile[tx][ty + rr] + ((n == k) ? g1 : 0.f);
        if (z == 0 && n < 1024) v *= QSCALE;   // fold softmax scale into Q weights
        WT[(size_t)n * K + k] = (bf16)v;
    }
}

// ---------------- bf16 MFMA GEMM (m97-style + swizzled DMA): C = A @ BT^T ----------------
// mode 0: fused qk+v. col<2048 -> qko (bias); col>=2048 -> vo + vT (scatter) + csum atomics
// mode 2: out fp32 = acc (gains pre-folded)
template<int BN>
__global__ __launch_bounds__(256, 3)
void gemm_bt(const bf16* __restrict__ A, const bf16* __restrict__ BT,
             int M, int N, int K, void* __restrict__ Cout, bf16* __restrict__ C2,
             bf16* __restrict__ C2T, float* __restrict__ csum,
             int mode, const float* __restrict__ aux) {
    __shared__ __align__(16) bf16 As[128][64];
    __shared__ __align__(16) bf16 Bs[BN][64];
    constexpr int JF = BN / 32;
    int m0 = blockIdx.y * 128, n0 = blockIdx.x * BN;
    int t = threadIdx.x, lane = t & 63, w = t >> 6;
    int wm = (w >> 1) * 64, wn = (w & 1) * (BN / 2);
    int lrow = lane & 15, lkg = lane >> 4;

    f32x4 acc[4][JF] = {};

    int gsw = ((lane & 7) ^ ((lane >> 3) & 7)) * 8;
    const bf16* Ab = A + (size_t)(m0 + w * 8 + (lane >> 3)) * K + gsw;
    const bf16* Bb = BT + (size_t)(n0 + w * 8 + (lane >> 3)) * K + gsw;

    for (int k0 = 0; k0 < K; k0 += 64) {
        #pragma unroll
        for (int p = 0; p < 4; p++)
            async16(Ab + (size_t)(p * 32) * K + k0, &As[p * 32 + w * 8][0]);
        #pragma unroll
        for (int p = 0; p < BN / 32; p++)
            async16(Bb + (size_t)(p * 32) * K + k0, &Bs[p * 32 + w * 8][0]);
        __syncthreads();
        #pragma unroll
        for (int ks = 0; ks < 2; ks++) {
            bf16x8 af[4], bfr[JF];
            int phys = (((4 * ks + lkg) ^ (lrow & 7)) << 3);
            #pragma unroll
            for (int i = 0; i < 4; i++) af[i] = *(const bf16x8*)&As[wm + i * 16 + lrow][phys];
            #pragma unroll
            for (int j = 0; j < JF; j++) bfr[j] = *(const bf16x8*)&Bs[wn + j * 16 + lrow][phys];
            #pragma unroll
            for (int i = 0; i < 4; i++)
                #pragma unroll
                for (int j = 0; j < JF; j++)
                    acc[i][j] = __builtin_amdgcn_mfma_f32_16x16x32_bf16(af[i], bfr[j], acc[i][j], 0, 0, 0);
        }
        __syncthreads();
    }

    int rgrp = (lane >> 4) * 4;
    #pragma unroll
    for (int i = 0; i < 4; i++) {
        #pragma unroll
        for (int j = 0; j < JF; j++) {
            int col = n0 + wn + j * 16 + lrow;
            int row0 = m0 + wm + i * 16 + rgrp;
            if (mode == 0) {
                if (col < 2048) {
                    float bb = aux[col];
                    if (col < 1024) bb *= QSCALE;
                    #pragma unroll
                    for (int reg = 0; reg < 4; reg++)
                        ((bf16*)Cout)[(size_t)(row0 + reg) * 2048 + col] = (bf16)(acc[i][j][reg] + bb);
                } else {
                    int c = col - 2048;
                    Pack4 p4;
                    #pragma unroll
                    for (int reg = 0; reg < 4; reg++) {
                        bf16 hv = (bf16)acc[i][j][reg];
                        C2[(size_t)(row0 + reg) * 1024 + c] = hv;
                        p4.h[reg] = hv;
                    }
                    *(uint2*)&C2T[(size_t)c * 4096 + row0] = p4.u2;
                }
            } else {
                #pragma unroll
                for (int reg = 0; reg < 4; reg++)
                    ((float*)Cout)[(size_t)(row0 + reg) * N + col] = acc[i][j][reg];
            }
        }
    }

    // V-blocks: per-column sums over this wave's 64 rows -> one atomicAdd per csum cell
    if (mode == 0 && n0 >= 2048) {
        int chunk = (m0 + wm) >> 6;   // == b*32 + local chunk
        #pragma unroll
        for (int j = 0; j < JF; j++) {
            float s = 0.f;
            #pragma unroll
            for (int i = 0; i < 4; i++)
                #pragma unroll
                for (int reg = 0; reg < 4; reg++) s += acc[i][j][reg];
            s += __shfl_xor(s, 16, 64);
            s += __shfl_xor(s, 32, 64);
            if (lkg == 0)
                atomicAdd(&csum[(size_t)chunk * 1024 + (n0 - 2048 + wn + j * 16 + lrow)], s);
        }
    }
}

// ---------------- flash split-K, fixed-base softmax (no running max) ----------------
__global__ __launch_bounds__(256, 3)
void flash_split(const bf16* __restrict__ qk, const bf16* __restrict__ vT,
                 bf16* __restrict__ Opart, float* __restrict__ lbuf,
                 int S, int E, int H) {
    __shared__ __align__(16) bf16 Ks[2][64][64];   // swizzled DMA: [key][d-group ^ (key&7)]
    __shared__ __align__(16) bf16 Vt[2][64][64];   // swizzled DMA: [d][key-group ^ (d&7)]
    __shared__ __align__(16) bf16 Ps[4][32][72];   // per-wave: [qrow-local][key]

    int item = blockIdx.x, bh = blockIdx.y;
    int qt = QT_OF[item], ck = CK_OF[item];
    int b = bh >> 4, h = bh & 15;
    int q0 = qt * 128;
    int ktstart = ck * 8;
    int nloc = min(8, 2 * (qt + 1) - ktstart);
    int t = threadIdx.x, lane = t & 63, w = t >> 6;
    int lrow = lane & 15, lkg = lane >> 4;
    const int ld = 2 * E;

    const bf16* Qg  = qk + (size_t)(b * S + q0) * ld + h * 64;
    const bf16* Kg0 = qk + (size_t)(b * S) * ld + E + h * 64;
    const bf16* Vg0 = vT + (size_t)(h * 64) * 4096 + b * 2048;

    bf16x8 qf[2][2];
    #pragma unroll
    for (int qg = 0; qg < 2; qg++)
        #pragma unroll
        for (int ks = 0; ks < 2; ks++)
            qf[qg][ks] = *(const bf16x8*)&Qg[(size_t)(32 * w + 16 * qg + lrow) * ld + ks * 32 + lkg * 8];

    f32x4 oacc[4][2] = {};
    float lrun[2] = {0.f, 0.f};

    auto stage = [&](int buf, int kt) {
        int k0 = kt * 64;
        int g = (lane & 7) ^ ((lane >> 3) & 7);
        #pragma unroll
        for (int p = 0; p < 2; p++) {
            int row = w * 8 + p * 32 + (lane >> 3);
            async16(Kg0 + (size_t)(k0 + row) * ld + g * 8, &Ks[buf][row][(lane & 7) * 8]);
            async16(Vg0 + (size_t)row * 4096 + k0 + g * 8, &Vt[buf][row][(lane & 7) * 8]);
        }
    };

    stage(0, ktstart);
    for (int kl = 0; kl < nloc; kl++) {
        int buf = kl & 1;
        int k0 = (ktstart + kl) * 64;
        __syncthreads();
        if (kl + 1 < nloc) stage(1 - buf, ktstart + kl + 1);

        bool skip0 = (k0 > q0 + 32 * w + 15);
        bool skip1 = (k0 > q0 + 32 * w + 31);
        if (skip0 && skip1) continue;

        f32x4 sacc[2][4] = {};
        #pragma unroll
        for (int ks = 0; ks < 2; ks++) {
            bf16x8 ak[4];
            int phys = (((4 * ks + lkg) ^ (lrow & 7)) << 3);
            #pragma unroll
            for (int kf = 0; kf < 4; kf++)
                ak[kf] = *(const bf16x8*)&Ks[buf][16 * kf + lrow][phys];
            #pragma unroll
            for (int kf = 0; kf < 4; kf++)
                sacc[0][kf] = __builtin_amdgcn_mfma_f32_16x16x32_bf16(ak[kf], qf[0][ks], sacc[0][kf], 0, 0, 0);
            if (!skip1)
                #pragma unroll
                for (int kf = 0; kf < 4; kf++)
                    sacc[1][kf] = __builtin_amdgcn_mfma_f32_16x16x32_bf16(ak[kf], qf[1][ks], sacc[1][kf], 0, 0, 0);
        }

        #pragma unroll
        for (int qg = 0; qg < 2; qg++) {
            if ((qg == 0 && skip0) || (qg == 1 && skip1)) continue;
            int kmin = q0 + 32 * w + 16 * qg;
            bool diag = (k0 + 63 > kmin);
            int qrow = kmin + lrow;
            float rsum = 0.f;
            #pragma unroll
            for (int kf = 0; kf < 4; kf++) {
                Pack4 p4;
                #pragma unroll
                for (int r = 0; r < 4; r++) {
                    float sv = sacc[qg][kf][r];
                    if (diag && (k0 + 16 * kf + 4 * lkg + r > qrow)) sv = -1e30f;
                    float p = exp2f(sv);
                    rsum += p;
                    p4.h[r] = (bf16)p;
                }
                *(uint2*)&Ps[w][16 * qg + lrow][16 * kf + 4 * lkg] = p4.u2;
            }
            lrun[qg] += rsum;
        }

        #pragma unroll
        for (int ks = 0; ks < 2; ks++) {
            bf16x8 av[4];
            int phys = (((4 * ks + lkg) ^ (lrow & 7)) << 3);
            #pragma unroll
            for (int df = 0; df < 4; df++)
                av[df] = *(const bf16x8*)&Vt[buf][16 * df + lrow][phys];
            #pragma unroll
            for (int qg = 0; qg < 2; qg++) {
                if ((qg == 0 && skip0) || (qg == 1 && skip1)) continue;
                bf16x8 bp = *(const bf16x8*)&Ps[w][16 * qg + lrow][ks * 32 + lkg * 8];
                #pragma unroll
                for (int df = 0; df < 4; df++)
                    oacc[df][qg] = __builtin_amdgcn_mfma_f32_16x16x32_bf16(av[df], bp, oacc[df][qg], 0, 0, 0);
            }
        }
    }

    size_t ibase = (size_t)(bh * 40 + item) * 128;
    #pragma unroll
    for (int qg = 0; qg < 2; qg++) {
        #pragma unroll
        for (int df = 0; df < 4; df++) {
            Pack4 p4;
            #pragma unroll
            for (int r = 0; r < 4; r++) p4.h[r] = (bf16)oacc[df][qg][r];
            *(uint2*)&Ps[w][16 * qg + lrow][16 * df + 4 * lkg] = p4.u2;
        }
        float l = lrun[qg];
        l += __shfl_xor(l, 16, 64);
        l += __shfl_xor(l, 32, 64);
        if (lkg == 0) lbuf[ibase + w * 32 + qg * 16 + lrow] = l;
    }
    int r_l = lane >> 1, half = lane & 1;
    bf16* orow = Opart + (ibase + w * 32 + r_l) * 64 + 32 * half;
    #pragma unroll
    for (int c = 0; c < 4; c++)
        *(uint4*)&orow[8 * c] = *(const uint4*)&Ps[w][r_l][32 * half + 8 * c];
}

// ---------------- fused merge + combine (bf16 LDS; local exclusive scan of raw csum) ----------------
__global__ void merge_combine(const bf16* __restrict__ Opart, const float* __restrict__ lbuf,
                              const bf16* __restrict__ v, const float* __restrict__ csum,
                              const float* __restrict__ gr, const float* __restrict__ gs,
                              const float* __restrict__ gc, bf16* __restrict__ ctx) {
    const int S = 2048, E = 1024;
    int qt = blockIdx.x, bh = blockIdx.y;
    int b = bh >> 4, h = bh & 15;
    int nc = (qt >> 2) + 1, base = BASE_OF[qt];
    int q0 = qt * 128;
    int t = threadIdx.x;

    __shared__ bf16 osm[128][66];

    // phase A: merge partials -> normalized O (bf16) in LDS
    {
        int r = t >> 1, dh = (t & 1) * 32;
        float L = 0.f;
        for (int c = 0; c < nc; c++)
            L += lbuf[(size_t)(bh * 40 + base + c) * 128 + r];
        float inv = 1.f / L;
        float o[32] = {};
        for (int c = 0; c < nc; c++) {
            const bf16* src = Opart + ((size_t)(bh * 40 + base + c) * 128 + r) * 64 + dh;
            #pragma unroll
            for (int g = 0; g < 4; g++) {
                U16x8 u; u.u = *(const uint4*)&src[g * 8];
                #pragma unroll
                for (int j = 0; j < 8; j++) o[g * 8 + j] += (float)u.h[j];
            }
        }
        #pragma unroll
        for (int j = 0; j < 32; j++) osm[r][dh + j] = (bf16)(o[j] * inv);
    }
    __syncthreads();

    // phase B: local exclusive scan over raw chunk sums, then combine
    if (t < 128) {
        int c = t & 63, ckk = t >> 6;
        int col = h * 64 + c;
        float grh = gr[h], gsh = gs[h], gch = gc[h];
        int chunk = (q0 >> 6) + ckk;                  // local chunk in [0,32)
        float run = 0.f;
        for (int j = 0; j < chunk; j++)
            run += csum[((size_t)b * 32 + j) * E + col];
        const bf16* vp = v + ((size_t)b * S + chunk * 64) * E + col;
        bf16* cp = ctx + ((size_t)b * S + chunk * 64) * E + col;
        for (int i = 0; i < 64; i++) {
            int row = chunk * 64 + i;
            float vv = (float)vp[(size_t)i * E];
            run += vv;
            float pm = run / (float)(row + 1);
            cp[(size_t)i * E] = (bf16)(grh * (float)osm[ckk * 64 + i][c] + gsh * vv - gch * pm);
        }
    }
}

extern "C" void kernel_launch(void* const* d_in, const int* in_sizes, int n_in,
                              void* d_out, int out_size, void* d_ws, size_t ws_size,
                              hipStream_t stream) {
    const float* hs  = (const float*)d_in[0];
    const float* qkw = (const float*)d_in[1];
    const float* qkb = (const float*)d_in[2];
    const float* vw  = (const float*)d_in[3];
    const float* vrg = (const float*)d_in[4];
    const float* vsg = (const float*)d_in[5];
    const float* pw  = (const float*)d_in[6];
    const float* prg = (const float*)d_in[7];
    const float* psg = (const float*)d_in[8];
    const float* amr = (const float*)d_in[9];
    const float* ams = (const float*)d_in[10];
    const float* amc = (const float*)d_in[11];
    float* out = (float*)d_out;

    const int B = 2, S = 2048, E = 1024, H = 16, M = B * S;
    char* ws = (char*)d_ws;
    size_t off = 0;
    auto alloc = [&](size_t bytes) { void* p = ws + off; off += (bytes + 255) & ~255ull; return p; };
    bf16* hsb   = (bf16*)alloc((size_t)M * E * 2);
    bf16* qkvT  = (bf16*)alloc((size_t)3 * E * E * 2);
    bf16* pwT   = (bf16*)alloc((size_t)E * E * 2);
    bf16* qko   = (bf16*)alloc((size_t)M * 2 * E * 2);
    bf16* vo    = (bf16*)alloc((size_t)M * E * 2);
    bf16* vT    = (bf16*)alloc((size_t)E * M * 2);
    float* csum = (float*)alloc((size_t)B * 32 * E * 4);
    bf16* ctxb  = (bf16*)alloc((size_t)M * E * 2);
    bf16* Opart = (bf16*)alloc((size_t)32 * 40 * 128 * 64 * 2);
    float* lbuf = (float*)alloc((size_t)32 * 40 * 128 * 4);

    hipMemsetAsync(csum, 0, (size_t)B * 32 * E * 4, stream);
    prep<<<8192, 256, 0, stream>>>(hs, hsb, qkw, vw, pw, qkvT, pwT, vrg, vsg, prg, psg);

    gemm_bt<128><<<dim3(3 * E / 128, M / 128), 256, 0, stream>>>(
        hsb, qkvT, M, 3 * E, E, qko, vo, vT, csum, 0, qkb);

    flash_split<<<dim3(40, 32), 256, 0, stream>>>(qko, vT, Opart, lbuf, S, E, H);
    merge_combine<<<dim3(16, 32), 256, 0, stream>>>(Opart, lbuf, vo, csum, amr, ams, amc, ctxb);

    gemm_bt<64><<<dim3(E / 64, M / 128), 256, 0, stream>>>(
        ctxb, pwT, M, E, E, out, nullptr, nullptr, nullptr, 2, nullptr);
}

// Round 8
// 209.425 us; speedup vs baseline: 1.0808x; 1.0338x over previous
//
#include <hip/hip_runtime.h>

typedef __bf16 bf16;
typedef __attribute__((ext_vector_type(8))) __bf16 bf16x8;
typedef __attribute__((ext_vector_type(4))) float f32x4;

union U16x8 { uint4 u; bf16 h[8]; };
union Pack4 { uint2 u2; bf16 h[4]; };

#define QSCALE 0.18033688011112042f   // log2(e)/sqrt(64)

__device__ __forceinline__ void async16(const bf16* g, bf16* l) {
    __builtin_amdgcn_global_load_lds((const __attribute__((address_space(1))) void*)g,
                                     (__attribute__((address_space(3))) void*)l, 16, 0, 0);
}

// split-K item tables: 40 items per (b,h), ordered heaviest-first
__device__ const int QT_OF[40] = {15,15,15,15,14,14,14,14,13,13,13,13,12,12,12,12,
                                  11,11,11,10,10,10,9,9,9,8,8,8,7,7,6,6,5,5,4,4,3,2,1,0};
__device__ const int CK_OF[40] = {0,1,2,3,0,1,2,3,0,1,2,3,0,1,2,3,
                                  0,1,2,0,1,2,0,1,2,0,1,2,0,1,0,1,0,1,0,1,0,0,0,0};
__device__ const int BASE_OF[16] = {39,38,37,36,34,32,30,28,25,22,19,16,12,8,4,0};

// ---------------- prep: csum zero + fp32->bf16 convert + 3 weight transposes ----------------
// blocks 0..7: zero csum; 8..4103: conv; 4104..8199: weight transposes
__global__ void prep(const float* __restrict__ hs, bf16* __restrict__ hsb,
                     const float* __restrict__ qkw, const float* __restrict__ vw,
                     const float* __restrict__ pw, bf16* __restrict__ qkvT,
                     bf16* __restrict__ pwT, float* __restrict__ csum,
                     const float* __restrict__ vrg, const float* __restrict__ vsg,
                     const float* __restrict__ prg, const float* __restrict__ psg) {
    const int K = 1024;
    int bx = blockIdx.x;
    if (bx < 8) {
        // zero 512 KB csum: 8 blocks x 256 threads x 16 float4
        float4* p = (float4*)csum + (bx * 256 + threadIdx.x) * 16;
        #pragma unroll
        for (int i = 0; i < 16; i++) p[i] = make_float4(0.f, 0.f, 0.f, 0.f);
        return;
    }
    if (bx < 4104) {
        int i = ((bx - 8) * 256 + threadIdx.x) * 4;
        float4 f = *(const float4*)(hs + i);
        hsb[i + 0] = (bf16)f.x; hsb[i + 1] = (bf16)f.y;
        hsb[i + 2] = (bf16)f.z; hsb[i + 3] = (bf16)f.w;
        return;
    }
    int r = bx - 4104;
    int z = r < 2048 ? 0 : (r < 3072 ? 1 : 2);
    int q = z == 0 ? r : (z == 1 ? r - 2048 : r - 3072);
    int ntiles = z == 0 ? 64 : 32;
    int N = z == 0 ? 2048 : 1024;
    const float* W = z == 0 ? qkw : (z == 1 ? vw : pw);
    bf16* WT = z == 0 ? qkvT : (z == 1 ? qkvT + (size_t)2 * 1024 * 1024 : pwT);
    float g0 = z == 0 ? 1.f : (z == 1 ? vrg[0] : prg[0]);
    float g1 = z == 0 ? 0.f : (z == 1 ? vsg[0] : psg[0]);

    __shared__ float tile[32][33];
    int n0 = (q % ntiles) * 32, k0 = (q / ntiles) * 32;
    int tx = threadIdx.x & 31, ty = threadIdx.x >> 5;
    #pragma unroll
    for (int rr = 0; rr < 32; rr += 8)
        tile[ty + rr][tx] = W[(size_t)(k0 + ty + rr) * N + n0 + tx];
    __syncthreads();
    #pragma unroll
    for (int rr = 0; rr < 32; rr += 8) {
        int n = n0 + ty + rr, k = k0 + tx;
        float v = g0 * tile[tx][ty + rr] + ((n == k) ? g1 : 0.f);
        if (z == 0 && n < 1024) v *= QSCALE;   // fold softmax scale into Q weights
        WT[(size_t)n * K + k] = (bf16)v;
    }
}

// ---------------- bf16 MFMA GEMM, XCD-swizzled 1D grid: C = A @ BT^T ----------------
// grid = 32 * (N/BN); n = bid/32, m = (bid%8)*4 + (bid/8)%4  -> XCD keeps 4 A-bands in L2
// mode 0: fused qk+v. col<2048 -> qko (bias); col>=2048 -> vT (scatter) + csum32 atomics
// mode 2: out fp32 = acc (gains pre-folded)
template<int BN>
__global__ __launch_bounds__(256, 3)
void gemm_bt(const bf16* __restrict__ A, const bf16* __restrict__ BT,
             int M, int N, int K, void* __restrict__ Cout,
             bf16* __restrict__ C2T, float* __restrict__ csum,
             int mode, const float* __restrict__ aux) {
    __shared__ __align__(16) bf16 As[128][64];
    __shared__ __align__(16) bf16 Bs[BN][64];
    constexpr int JF = BN / 32;
    int bid = blockIdx.x;
    int g32 = bid & 31;
    int m0 = ((g32 & 7) * 4 + (g32 >> 3)) * 128;
    int n0 = (bid >> 5) * BN;
    int t = threadIdx.x, lane = t & 63, w = t >> 6;
    int wm = (w >> 1) * 64, wn = (w & 1) * (BN / 2);
    int lrow = lane & 15, lkg = lane >> 4;

    f32x4 acc[4][JF] = {};

    int gsw = ((lane & 7) ^ ((lane >> 3) & 7)) * 8;
    const bf16* Ab = A + (size_t)(m0 + w * 8 + (lane >> 3)) * K + gsw;
    const bf16* Bb = BT + (size_t)(n0 + w * 8 + (lane >> 3)) * K + gsw;

    for (int k0 = 0; k0 < K; k0 += 64) {
        #pragma unroll
        for (int p = 0; p < 4; p++)
            async16(Ab + (size_t)(p * 32) * K + k0, &As[p * 32 + w * 8][0]);
        #pragma unroll
        for (int p = 0; p < BN / 32; p++)
            async16(Bb + (size_t)(p * 32) * K + k0, &Bs[p * 32 + w * 8][0]);
        __syncthreads();
        #pragma unroll
        for (int ks = 0; ks < 2; ks++) {
            bf16x8 af[4], bfr[JF];
            int phys = (((4 * ks + lkg) ^ (lrow & 7)) << 3);
            #pragma unroll
            for (int i = 0; i < 4; i++) af[i] = *(const bf16x8*)&As[wm + i * 16 + lrow][phys];
            #pragma unroll
            for (int j = 0; j < JF; j++) bfr[j] = *(const bf16x8*)&Bs[wn + j * 16 + lrow][phys];
            #pragma unroll
            for (int i = 0; i < 4; i++)
                #pragma unroll
                for (int j = 0; j < JF; j++)
                    acc[i][j] = __builtin_amdgcn_mfma_f32_16x16x32_bf16(af[i], bfr[j], acc[i][j], 0, 0, 0);
        }
        __syncthreads();
    }

    int rgrp = (lane >> 4) * 4;
    #pragma unroll
    for (int i = 0; i < 4; i++) {
        #pragma unroll
        for (int j = 0; j < JF; j++) {
            int col = n0 + wn + j * 16 + lrow;
            int row0 = m0 + wm + i * 16 + rgrp;
            if (mode == 0) {
                if (col < 2048) {
                    float bb = aux[col];
                    if (col < 1024) bb *= QSCALE;
                    #pragma unroll
                    for (int reg = 0; reg < 4; reg++)
                        ((bf16*)Cout)[(size_t)(row0 + reg) * 2048 + col] = (bf16)(acc[i][j][reg] + bb);
                } else {
                    int c = col - 2048;
                    Pack4 p4;
                    #pragma unroll
                    for (int reg = 0; reg < 4; reg++) p4.h[reg] = (bf16)acc[i][j][reg];
                    *(uint2*)&C2T[(size_t)c * 4096 + row0] = p4.u2;
                }
            } else {
                #pragma unroll
                for (int reg = 0; reg < 4; reg++)
                    ((float*)Cout)[(size_t)(row0 + reg) * N + col] = acc[i][j][reg];
            }
        }
    }

    // V-blocks: 32-row column sums -> csum32 atomics (one per (chunk32, col))
    if (mode == 0 && n0 >= 2048) {
        int chunkb = (m0 + wm) >> 5;   // global 32-row chunk index (row/32)
        #pragma unroll
        for (int j = 0; j < JF; j++) {
            float s0 = 0.f, s1 = 0.f;
            #pragma unroll
            for (int reg = 0; reg < 4; reg++) {
                s0 += acc[0][j][reg] + acc[1][j][reg];
                s1 += acc[2][j][reg] + acc[3][j][reg];
            }
            s0 += __shfl_xor(s0, 16, 64); s0 += __shfl_xor(s0, 32, 64);
            s1 += __shfl_xor(s1, 16, 64); s1 += __shfl_xor(s1, 32, 64);
            if (lkg == 0) {
                int col = n0 - 2048 + wn + j * 16 + lrow;
                atomicAdd(&csum[(size_t)chunkb * 1024 + col], s0);
                atomicAdd(&csum[(size_t)(chunkb + 1) * 1024 + col], s1);
            }
        }
    }
}

// ---------------- flash split-K, fixed-base softmax (no running max) ----------------
__global__ __launch_bounds__(256, 3)
void flash_split(const bf16* __restrict__ qk, const bf16* __restrict__ vT,
                 bf16* __restrict__ Opart, float* __restrict__ lbuf,
                 int S, int E, int H) {
    __shared__ __align__(16) bf16 Ks[2][64][64];   // swizzled DMA: [key][d-group ^ (key&7)]
    __shared__ __align__(16) bf16 Vt[2][64][64];   // swizzled DMA: [d][key-group ^ (d&7)]
    __shared__ __align__(16) bf16 Ps[4][32][72];   // per-wave: [qrow-local][key]

    int item = blockIdx.x, bh = blockIdx.y;
    int qt = QT_OF[item], ck = CK_OF[item];
    int b = bh >> 4, h = bh & 15;
    int q0 = qt * 128;
    int ktstart = ck * 8;
    int nloc = min(8, 2 * (qt + 1) - ktstart);
    int t = threadIdx.x, lane = t & 63, w = t >> 6;
    int lrow = lane & 15, lkg = lane >> 4;
    const int ld = 2 * E;

    const bf16* Qg  = qk + (size_t)(b * S + q0) * ld + h * 64;
    const bf16* Kg0 = qk + (size_t)(b * S) * ld + E + h * 64;
    const bf16* Vg0 = vT + (size_t)(h * 64) * 4096 + b * 2048;

    bf16x8 qf[2][2];
    #pragma unroll
    for (int qg = 0; qg < 2; qg++)
        #pragma unroll
        for (int ks = 0; ks < 2; ks++)
            qf[qg][ks] = *(const bf16x8*)&Qg[(size_t)(32 * w + 16 * qg + lrow) * ld + ks * 32 + lkg * 8];

    f32x4 oacc[4][2] = {};
    float lrun[2] = {0.f, 0.f};

    auto stage = [&](int buf, int kt) {
        int k0 = kt * 64;
        int g = (lane & 7) ^ ((lane >> 3) & 7);
        #pragma unroll
        for (int p = 0; p < 2; p++) {
            int row = w * 8 + p * 32 + (lane >> 3);
            async16(Kg0 + (size_t)(k0 + row) * ld + g * 8, &Ks[buf][row][(lane & 7) * 8]);
            async16(Vg0 + (size_t)row * 4096 + k0 + g * 8, &Vt[buf][row][(lane & 7) * 8]);
        }
    };

    stage(0, ktstart);
    for (int kl = 0; kl < nloc; kl++) {
        int buf = kl & 1;
        int k0 = (ktstart + kl) * 64;
        __syncthreads();
        if (kl + 1 < nloc) stage(1 - buf, ktstart + kl + 1);

        bool skip0 = (k0 > q0 + 32 * w + 15);
        bool skip1 = (k0 > q0 + 32 * w + 31);
        if (skip0 && skip1) continue;

        f32x4 sacc[2][4] = {};
        #pragma unroll
        for (int ks = 0; ks < 2; ks++) {
            bf16x8 ak[4];
            int phys = (((4 * ks + lkg) ^ (lrow & 7)) << 3);
            #pragma unroll
            for (int kf = 0; kf < 4; kf++)
                ak[kf] = *(const bf16x8*)&Ks[buf][16 * kf + lrow][phys];
            #pragma unroll
            for (int kf = 0; kf < 4; kf++)
                sacc[0][kf] = __builtin_amdgcn_mfma_f32_16x16x32_bf16(ak[kf], qf[0][ks], sacc[0][kf], 0, 0, 0);
            if (!skip1)
                #pragma unroll
                for (int kf = 0; kf < 4; kf++)
                    sacc[1][kf] = __builtin_amdgcn_mfma_f32_16x16x32_bf16(ak[kf], qf[1][ks], sacc[1][kf], 0, 0, 0);
        }

        #pragma unroll
        for (int qg = 0; qg < 2; qg++) {
            if ((qg == 0 && skip0) || (qg == 1 && skip1)) continue;
            int kmin = q0 + 32 * w + 16 * qg;
            bool diag = (k0 + 63 > kmin);
            int qrow = kmin + lrow;
            float rsum = 0.f;
            #pragma unroll
            for (int kf = 0; kf < 4; kf++) {
                Pack4 p4;
                #pragma unroll
                for (int r = 0; r < 4; r++) {
                    float sv = sacc[qg][kf][r];
                    if (diag && (k0 + 16 * kf + 4 * lkg + r > qrow)) sv = -1e30f;
                    float p = exp2f(sv);
                    rsum += p;
                    p4.h[r] = (bf16)p;
                }
                *(uint2*)&Ps[w][16 * qg + lrow][16 * kf + 4 * lkg] = p4.u2;
            }
            lrun[qg] += rsum;
        }

        #pragma unroll
        for (int ks = 0; ks < 2; ks++) {
            bf16x8 av[4];
            int phys = (((4 * ks + lkg) ^ (lrow & 7)) << 3);
            #pragma unroll
            for (int df = 0; df < 4; df++)
                av[df] = *(const bf16x8*)&Vt[buf][16 * df + lrow][phys];
            #pragma unroll
            for (int qg = 0; qg < 2; qg++) {
                if ((qg == 0 && skip0) || (qg == 1 && skip1)) continue;
                bf16x8 bp = *(const bf16x8*)&Ps[w][16 * qg + lrow][ks * 32 + lkg * 8];
                #pragma unroll
                for (int df = 0; df < 4; df++)
                    oacc[df][qg] = __builtin_amdgcn_mfma_f32_16x16x32_bf16(av[df], bp, oacc[df][qg], 0, 0, 0);
            }
        }
    }

    size_t ibase = (size_t)(bh * 40 + item) * 128;
    #pragma unroll
    for (int qg = 0; qg < 2; qg++) {
        #pragma unroll
        for (int df = 0; df < 4; df++) {
            Pack4 p4;
            #pragma unroll
            for (int r = 0; r < 4; r++) p4.h[r] = (bf16)oacc[df][qg][r];
            *(uint2*)&Ps[w][16 * qg + lrow][16 * df + 4 * lkg] = p4.u2;
        }
        float l = lrun[qg];
        l += __shfl_xor(l, 16, 64);
        l += __shfl_xor(l, 32, 64);
        if (lkg == 0) lbuf[ibase + w * 32 + qg * 16 + lrow] = l;
    }
    int r_l = lane >> 1, half = lane & 1;
    bf16* orow = Opart + (ibase + w * 32 + r_l) * 64 + 32 * half;
    #pragma unroll
    for (int c = 0; c < 4; c++)
        *(uint4*)&orow[8 * c] = *(const uint4*)&Ps[w][r_l][32 * half + 8 * c];
}

// ---------------- fused merge + combine (reads V from vT, register scan) ----------------
__global__ void merge_combine(const bf16* __restrict__ Opart, const float* __restrict__ lbuf,
                              const bf16* __restrict__ vT, const float* __restrict__ csum,
                              const float* __restrict__ gr, const float* __restrict__ gs,
                              const float* __restrict__ gc, bf16* __restrict__ ctx) {
    const int S = 2048, E = 1024;
    int qt = blockIdx.x, bh = blockIdx.y;
    int b = bh >> 4, h = bh & 15;
    int nc = (qt >> 2) + 1, base = BASE_OF[qt];
    int q0 = qt * 128;
    int t = threadIdx.x;

    __shared__ bf16 osm[128][66];

    // phase A: merge partials -> normalized O (bf16) in LDS
    {
        int r = t >> 1, dh = (t & 1) * 32;
        float L = 0.f;
        for (int c = 0; c < nc; c++)
            L += lbuf[(size_t)(bh * 40 + base + c) * 128 + r];
        float inv = 1.f / L;
        float o[32] = {};
        for (int c = 0; c < nc; c++) {
            const bf16* src = Opart + ((size_t)(bh * 40 + base + c) * 128 + r) * 64 + dh;
            #pragma unroll
            for (int g = 0; g < 4; g++) {
                U16x8 u; u.u = *(const uint4*)&src[g * 8];
                #pragma unroll
                for (int j = 0; j < 8; j++) o[g * 8 + j] += (float)u.h[j];
            }
        }
        #pragma unroll
        for (int j = 0; j < 32; j++) osm[r][dh + j] = (bf16)(o[j] * inv);
    }
    __syncthreads();

    // phase B: 256 threads = 64 cols x 4 sub-chunks of 32 rows; register scan
    {
        int c = t & 63, sc = t >> 6;
        int col = h * 64 + c;
        int row0 = q0 + sc * 32;                 // within-batch row
        float grh = gr[h], gsh = gs[h], gch = gc[h];
        // exclusive prefix over 32-row chunks
        float run = 0.f;
        int cend = qt * 4 + sc;
        for (int j = 0; j < cend; j++)
            run += csum[((size_t)b * 64 + j) * E + col];
        // V values: contiguous in vT
        const bf16* vrow = vT + (size_t)col * 4096 + b * 2048 + row0;
        U16x8 vv[4];
        #pragma unroll
        for (int g = 0; g < 4; g++) vv[g].u = *(const uint4*)&vrow[g * 8];
        bf16* cp = ctx + ((size_t)(b * S + row0)) * E + col;
        #pragma unroll
        for (int i = 0; i < 32; i++) {
            float v = (float)vv[i >> 3].h[i & 7];
            run += v;
            float pm = run / (float)(row0 + i + 1);
            cp[(size_t)i * E] = (bf16)(grh * (float)osm[sc * 32 + i][c] + gsh * v - gch * pm);
        }
    }
}

extern "C" void kernel_launch(void* const* d_in, const int* in_sizes, int n_in,
                              void* d_out, int out_size, void* d_ws, size_t ws_size,
                              hipStream_t stream) {
    const float* hs  = (const float*)d_in[0];
    const float* qkw = (const float*)d_in[1];
    const float* qkb = (const float*)d_in[2];
    const float* vw  = (const float*)d_in[3];
    const float* vrg = (const float*)d_in[4];
    const float* vsg = (const float*)d_in[5];
    const float* pw  = (const float*)d_in[6];
    const float* prg = (const float*)d_in[7];
    const float* psg = (const float*)d_in[8];
    const float* amr = (const float*)d_in[9];
    const float* ams = (const float*)d_in[10];
    const float* amc = (const float*)d_in[11];
    float* out = (float*)d_out;

    const int B = 2, S = 2048, E = 1024, H = 16, M = B * S;
    char* ws = (char*)d_ws;
    size_t off = 0;
    auto alloc = [&](size_t bytes) { void* p = ws + off; off += (bytes + 255) & ~255ull; return p; };
    bf16* hsb   = (bf16*)alloc((size_t)M * E * 2);
    bf16* qkvT  = (bf16*)alloc((size_t)3 * E * E * 2);
    bf16* pwT   = (bf16*)alloc((size_t)E * E * 2);
    bf16* qko   = (bf16*)alloc((size_t)M * 2 * E * 2);
    bf16* vT    = (bf16*)alloc((size_t)E * M * 2);
    float* csum = (float*)alloc((size_t)128 * E * 4);   // 32-row chunks: 128 x 1024 fp32
    bf16* ctxb  = (bf16*)alloc((size_t)M * E * 2);
    bf16* Opart = (bf16*)alloc((size_t)32 * 40 * 128 * 64 * 2);
    float* lbuf = (float*)alloc((size_t)32 * 40 * 128 * 4);

    prep<<<8200, 256, 0, stream>>>(hs, hsb, qkw, vw, pw, qkvT, pwT, csum, vrg, vsg, prg, psg);

    gemm_bt<128><<<32 * (3 * E / 128), 256, 0, stream>>>(
        hsb, qkvT, M, 3 * E, E, qko, vT, csum, 0, qkb);

    flash_split<<<dim3(40, 32), 256, 0, stream>>>(qko, vT, Opart, lbuf, S, E, H);
    merge_combine<<<dim3(16, 32), 256, 0, stream>>>(Opart, lbuf, vT, csum, amr, ams, amc, ctxb);

    gemm_bt<64><<<32 * (E / 64), 256, 0, stream>>>(
        ctxb, pwT, M, E, E, out, nullptr, nullptr, 2, nullptr);
}

// Round 9
// 206.904 us; speedup vs baseline: 1.0940x; 1.0122x over previous
//
#include <hip/hip_runtime.h>

typedef __bf16 bf16;
typedef __attribute__((ext_vector_type(8))) __bf16 bf16x8;
typedef __attribute__((ext_vector_type(4))) float f32x4;

union U16x8 { uint4 u; bf16 h[8]; };
union Pack4 { uint2 u2; bf16 h[4]; };

#define QSCALE 0.18033688011112042f   // log2(e)/sqrt(64)

__device__ __forceinline__ void async16(const bf16* g, bf16* l) {
    __builtin_amdgcn_global_load_lds((const __attribute__((address_space(1))) void*)g,
                                     (__attribute__((address_space(3))) void*)l, 16, 0, 0);
}

// split-K item tables: 40 items per (b,h), ordered heaviest-first
__device__ const int QT_OF[40] = {15,15,15,15,14,14,14,14,13,13,13,13,12,12,12,12,
                                  11,11,11,10,10,10,9,9,9,8,8,8,7,7,6,6,5,5,4,4,3,2,1,0};
__device__ const int CK_OF[40] = {0,1,2,3,0,1,2,3,0,1,2,3,0,1,2,3,
                                  0,1,2,0,1,2,0,1,2,0,1,2,0,1,0,1,0,1,0,1,0,0,0,0};
__device__ const int BASE_OF[16] = {39,38,37,36,34,32,30,28,25,22,19,16,12,8,4,0};

// ---------------- prep: csum zero + fp32->bf16 convert + 3 weight transposes ----------------
__global__ void prep(const float* __restrict__ hs, bf16* __restrict__ hsb,
                     const float* __restrict__ qkw, const float* __restrict__ vw,
                     const float* __restrict__ pw, bf16* __restrict__ qkvT,
                     bf16* __restrict__ pwT, float* __restrict__ csum,
                     const float* __restrict__ vrg, const float* __restrict__ vsg,
                     const float* __restrict__ prg, const float* __restrict__ psg) {
    const int K = 1024;
    int bx = blockIdx.x;
    if (bx < 8) {
        float4* p = (float4*)csum + (bx * 256 + threadIdx.x) * 16;
        #pragma unroll
        for (int i = 0; i < 16; i++) p[i] = make_float4(0.f, 0.f, 0.f, 0.f);
        return;
    }
    if (bx < 4104) {
        int i = ((bx - 8) * 256 + threadIdx.x) * 4;
        float4 f = *(const float4*)(hs + i);
        hsb[i + 0] = (bf16)f.x; hsb[i + 1] = (bf16)f.y;
        hsb[i + 2] = (bf16)f.z; hsb[i + 3] = (bf16)f.w;
        return;
    }
    int r = bx - 4104;
    int z = r < 2048 ? 0 : (r < 3072 ? 1 : 2);
    int q = z == 0 ? r : (z == 1 ? r - 2048 : r - 3072);
    int ntiles = z == 0 ? 64 : 32;
    int N = z == 0 ? 2048 : 1024;
    const float* W = z == 0 ? qkw : (z == 1 ? vw : pw);
    bf16* WT = z == 0 ? qkvT : (z == 1 ? qkvT + (size_t)2 * 1024 * 1024 : pwT);
    float g0 = z == 0 ? 1.f : (z == 1 ? vrg[0] : prg[0]);
    float g1 = z == 0 ? 0.f : (z == 1 ? vsg[0] : psg[0]);

    __shared__ float tile[32][33];
    int n0 = (q % ntiles) * 32, k0 = (q / ntiles) * 32;
    int tx = threadIdx.x & 31, ty = threadIdx.x >> 5;
    #pragma unroll
    for (int rr = 0; rr < 32; rr += 8)
        tile[ty + rr][tx] = W[(size_t)(k0 + ty + rr) * N + n0 + tx];
    __syncthreads();
    #pragma unroll
    for (int rr = 0; rr < 32; rr += 8) {
        int n = n0 + ty + rr, k = k0 + tx;
        float v = g0 * tile[tx][ty + rr] + ((n == k) ? g1 : 0.f);
        if (z == 0 && n < 1024) v *= QSCALE;
        WT[(size_t)n * K + k] = (bf16)v;
    }
}

// ---------------- bf16 MFMA GEMM, XCD-swizzled 1D grid: C = A @ BT^T ----------------
// mode 0: fused qk+v. col<2048 -> qko (bias); col>=2048 -> vT (scatter) + csumT atomics
// mode 2: out fp32 = acc (gains pre-folded)
template<int BN>
__global__ __launch_bounds__(256, 3)
void gemm_bt(const bf16* __restrict__ A, const bf16* __restrict__ BT,
             int M, int N, int K, void* __restrict__ Cout,
             bf16* __restrict__ C2T, float* __restrict__ csum,
             int mode, const float* __restrict__ aux) {
    __shared__ __align__(16) bf16 As[128][64];
    __shared__ __align__(16) bf16 Bs[BN][64];
    constexpr int JF = BN / 32;
    int bid = blockIdx.x;
    int g32 = bid & 31;
    int m0 = ((g32 & 7) * 4 + (g32 >> 3)) * 128;
    int n0 = (bid >> 5) * BN;
    int t = threadIdx.x, lane = t & 63, w = t >> 6;
    int wm = (w >> 1) * 64, wn = (w & 1) * (BN / 2);
    int lrow = lane & 15, lkg = lane >> 4;

    f32x4 acc[4][JF] = {};

    int gsw = ((lane & 7) ^ ((lane >> 3) & 7)) * 8;
    const bf16* Ab = A + (size_t)(m0 + w * 8 + (lane >> 3)) * K + gsw;
    const bf16* Bb = BT + (size_t)(n0 + w * 8 + (lane >> 3)) * K + gsw;

    for (int k0 = 0; k0 < K; k0 += 64) {
        #pragma unroll
        for (int p = 0; p < 4; p++)
            async16(Ab + (size_t)(p * 32) * K + k0, &As[p * 32 + w * 8][0]);
        #pragma unroll
        for (int p = 0; p < BN / 32; p++)
            async16(Bb + (size_t)(p * 32) * K + k0, &Bs[p * 32 + w * 8][0]);
        __syncthreads();
        #pragma unroll
        for (int ks = 0; ks < 2; ks++) {
            bf16x8 af[4], bfr[JF];
            int phys = (((4 * ks + lkg) ^ (lrow & 7)) << 3);
            #pragma unroll
            for (int i = 0; i < 4; i++) af[i] = *(const bf16x8*)&As[wm + i * 16 + lrow][phys];
            #pragma unroll
            for (int j = 0; j < JF; j++) bfr[j] = *(const bf16x8*)&Bs[wn + j * 16 + lrow][phys];
            #pragma unroll
            for (int i = 0; i < 4; i++)
                #pragma unroll
                for (int j = 0; j < JF; j++)
                    acc[i][j] = __builtin_amdgcn_mfma_f32_16x16x32_bf16(af[i], bfr[j], acc[i][j], 0, 0, 0);
        }
        __syncthreads();
    }

    int rgrp = (lane >> 4) * 4;
    #pragma unroll
    for (int i = 0; i < 4; i++) {
        #pragma unroll
        for (int j = 0; j < JF; j++) {
            int col = n0 + wn + j * 16 + lrow;
            int row0 = m0 + wm + i * 16 + rgrp;
            if (mode == 0) {
                if (col < 2048) {
                    float bb = aux[col];
                    if (col < 1024) bb *= QSCALE;
                    #pragma unroll
                    for (int reg = 0; reg < 4; reg++)
                        ((bf16*)Cout)[(size_t)(row0 + reg) * 2048 + col] = (bf16)(acc[i][j][reg] + bb);
                } else {
                    int c = col - 2048;
                    Pack4 p4;
                    #pragma unroll
                    for (int reg = 0; reg < 4; reg++) p4.h[reg] = (bf16)acc[i][j][reg];
                    *(uint2*)&C2T[(size_t)c * 4096 + row0] = p4.u2;
                }
            } else {
                #pragma unroll
                for (int reg = 0; reg < 4; reg++)
                    ((float*)Cout)[(size_t)(row0 + reg) * N + col] = acc[i][j][reg];
            }
        }
    }

    // V-blocks: 32-row column sums -> transposed csum[col][chunk] atomics
    if (mode == 0 && n0 >= 2048) {
        int chunkb = (m0 + wm) >> 5;
        #pragma unroll
        for (int j = 0; j < JF; j++) {
            float s0 = 0.f, s1 = 0.f;
            #pragma unroll
            for (int reg = 0; reg < 4; reg++) {
                s0 += acc[0][j][reg] + acc[1][j][reg];
                s1 += acc[2][j][reg] + acc[3][j][reg];
            }
            s0 += __shfl_xor(s0, 16, 64); s0 += __shfl_xor(s0, 32, 64);
            s1 += __shfl_xor(s1, 16, 64); s1 += __shfl_xor(s1, 32, 64);
            if (lkg == 0) {
                int col = n0 - 2048 + wn + j * 16 + lrow;
                atomicAdd(&csum[(size_t)col * 128 + chunkb], s0);
                atomicAdd(&csum[(size_t)col * 128 + chunkb + 1], s1);
            }
        }
    }
}

// ---------------- flash split-K, fixed-base softmax, diag/non-diag split ----------------
__global__ __launch_bounds__(256, 3)
void flash_split(const bf16* __restrict__ qk, const bf16* __restrict__ vT,
                 bf16* __restrict__ Opart, float* __restrict__ lbuf,
                 int S, int E, int H) {
    __shared__ __align__(16) bf16 Ks[2][64][64];
    __shared__ __align__(16) bf16 Vt[2][64][64];
    __shared__ __align__(16) bf16 Ps[4][32][72];

    int item = blockIdx.x, bh = blockIdx.y;
    int qt = QT_OF[item], ck = CK_OF[item];
    int b = bh >> 4, h = bh & 15;
    int q0 = qt * 128;
    int ktstart = ck * 8;
    int nloc = min(8, 2 * (qt + 1) - ktstart);
    int t = threadIdx.x, lane = t & 63, w = t >> 6;
    int lrow = lane & 15, lkg = lane >> 4;
    const int ld = 2 * E;

    const bf16* Qg  = qk + (size_t)(b * S + q0) * ld + h * 64;
    const bf16* Kg0 = qk + (size_t)(b * S) * ld + E + h * 64;
    const bf16* Vg0 = vT + (size_t)(h * 64) * 4096 + b * 2048;

    bf16x8 qf[2][2];
    #pragma unroll
    for (int qg = 0; qg < 2; qg++)
        #pragma unroll
        for (int ks = 0; ks < 2; ks++)
            qf[qg][ks] = *(const bf16x8*)&Qg[(size_t)(32 * w + 16 * qg + lrow) * ld + ks * 32 + lkg * 8];

    f32x4 oacc[4][2] = {};
    float lrun[2] = {0.f, 0.f};

    auto stage = [&](int buf, int kt) {
        int k0 = kt * 64;
        int g = (lane & 7) ^ ((lane >> 3) & 7);
        #pragma unroll
        for (int p = 0; p < 2; p++) {
            int row = w * 8 + p * 32 + (lane >> 3);
            async16(Kg0 + (size_t)(k0 + row) * ld + g * 8, &Ks[buf][row][(lane & 7) * 8]);
            async16(Vg0 + (size_t)row * 4096 + k0 + g * 8, &Vt[buf][row][(lane & 7) * 8]);
        }
    };

    stage(0, ktstart);
    for (int kl = 0; kl < nloc; kl++) {
        int buf = kl & 1;
        int k0 = (ktstart + kl) * 64;
        __syncthreads();
        if (kl + 1 < nloc) stage(1 - buf, ktstart + kl + 1);

        bool skip0 = (k0 > q0 + 32 * w + 15);
        bool skip1 = (k0 > q0 + 32 * w + 31);
        if (skip0 && skip1) continue;

        f32x4 sacc[2][4] = {};
        #pragma unroll
        for (int ks = 0; ks < 2; ks++) {
            bf16x8 ak[4];
            int phys = (((4 * ks + lkg) ^ (lrow & 7)) << 3);
            #pragma unroll
            for (int kf = 0; kf < 4; kf++)
                ak[kf] = *(const bf16x8*)&Ks[buf][16 * kf + lrow][phys];
            #pragma unroll
            for (int kf = 0; kf < 4; kf++)
                sacc[0][kf] = __builtin_amdgcn_mfma_f32_16x16x32_bf16(ak[kf], qf[0][ks], sacc[0][kf], 0, 0, 0);
            if (!skip1)
                #pragma unroll
                for (int kf = 0; kf < 4; kf++)
                    sacc[1][kf] = __builtin_amdgcn_mfma_f32_16x16x32_bf16(ak[kf], qf[1][ks], sacc[1][kf], 0, 0, 0);
        }

        #pragma unroll
        for (int qg = 0; qg < 2; qg++) {
            if ((qg == 0 && skip0) || (qg == 1 && skip1)) continue;
            int kmin = q0 + 32 * w + 16 * qg;
            float rsum = 0.f;
            if (k0 + 63 <= kmin) {
                // non-diagonal: no masking needed
                #pragma unroll
                for (int kf = 0; kf < 4; kf++) {
                    Pack4 p4;
                    #pragma unroll
                    for (int r = 0; r < 4; r++) {
                        float p = exp2f(sacc[qg][kf][r]);
                        rsum += p;
                        p4.h[r] = (bf16)p;
                    }
                    *(uint2*)&Ps[w][16 * qg + lrow][16 * kf + 4 * lkg] = p4.u2;
                }
            } else {
                int qrow = kmin + lrow;
                #pragma unroll
                for (int kf = 0; kf < 4; kf++) {
                    Pack4 p4;
                    #pragma unroll
                    for (int r = 0; r < 4; r++) {
                        float sv = sacc[qg][kf][r];
                        if (k0 + 16 * kf + 4 * lkg + r > qrow) sv = -1e30f;
                        float p = exp2f(sv);
                        rsum += p;
                        p4.h[r] = (bf16)p;
                    }
                    *(uint2*)&Ps[w][16 * qg + lrow][16 * kf + 4 * lkg] = p4.u2;
                }
            }
            lrun[qg] += rsum;
        }

        #pragma unroll
        for (int ks = 0; ks < 2; ks++) {
            bf16x8 av[4];
            int phys = (((4 * ks + lkg) ^ (lrow & 7)) << 3);
            #pragma unroll
            for (int df = 0; df < 4; df++)
                av[df] = *(const bf16x8*)&Vt[buf][16 * df + lrow][phys];
            #pragma unroll
            for (int qg = 0; qg < 2; qg++) {
                if ((qg == 0 && skip0) || (qg == 1 && skip1)) continue;
                bf16x8 bp = *(const bf16x8*)&Ps[w][16 * qg + lrow][ks * 32 + lkg * 8];
                #pragma unroll
                for (int df = 0; df < 4; df++)
                    oacc[df][qg] = __builtin_amdgcn_mfma_f32_16x16x32_bf16(av[df], bp, oacc[df][qg], 0, 0, 0);
            }
        }
    }

    size_t ibase = (size_t)(bh * 40 + item) * 128;
    #pragma unroll
    for (int qg = 0; qg < 2; qg++) {
        #pragma unroll
        for (int df = 0; df < 4; df++) {
            Pack4 p4;
            #pragma unroll
            for (int r = 0; r < 4; r++) p4.h[r] = (bf16)oacc[df][qg][r];
            *(uint2*)&Ps[w][16 * qg + lrow][16 * df + 4 * lkg] = p4.u2;
        }
        float l = lrun[qg];
        l += __shfl_xor(l, 16, 64);
        l += __shfl_xor(l, 32, 64);
        if (lkg == 0) lbuf[ibase + w * 32 + qg * 16 + lrow] = l;
    }
    int r_l = lane >> 1, half = lane & 1;
    bf16* orow = Opart + (ibase + w * 32 + r_l) * 64 + 32 * half;
    #pragma unroll
    for (int c = 0; c < 4; c++)
        *(uint4*)&orow[8 * c] = *(const uint4*)&Ps[w][r_l][32 * half + 8 * c];
}

// ---------------- fused merge + combine (vectorized csum scan, V from vT) ----------------
__global__ void merge_combine(const bf16* __restrict__ Opart, const float* __restrict__ lbuf,
                              const bf16* __restrict__ vT, const float* __restrict__ csum,
                              const float* __restrict__ gr, const float* __restrict__ gs,
                              const float* __restrict__ gc, bf16* __restrict__ ctx) {
    const int S = 2048, E = 1024;
    int qt = blockIdx.x, bh = blockIdx.y;
    int b = bh >> 4, h = bh & 15;
    int nc = (qt >> 2) + 1, base = BASE_OF[qt];
    int q0 = qt * 128;
    int t = threadIdx.x;

    __shared__ bf16 osm[128][66];

    // phase A: merge partials -> normalized O (bf16) in LDS
    {
        int r = t >> 1, dh = (t & 1) * 32;
        float L = 0.f;
        for (int c = 0; c < nc; c++)
            L += lbuf[(size_t)(bh * 40 + base + c) * 128 + r];
        float inv = 1.f / L;
        float o[32] = {};
        for (int c = 0; c < nc; c++) {
            const bf16* src = Opart + ((size_t)(bh * 40 + base + c) * 128 + r) * 64 + dh;
            #pragma unroll
            for (int g = 0; g < 4; g++) {
                U16x8 u; u.u = *(const uint4*)&src[g * 8];
                #pragma unroll
                for (int j = 0; j < 8; j++) o[g * 8 + j] += (float)u.h[j];
            }
        }
        #pragma unroll
        for (int j = 0; j < 32; j++) osm[r][dh + j] = (bf16)(o[j] * inv);
    }
    __syncthreads();

    // phase B: 256 threads = 64 cols x 4 sub-chunks of 32 rows; vectorized prefix
    {
        int c = t & 63, sc = t >> 6;
        int col = h * 64 + c;
        int row0 = q0 + sc * 32;
        float grh = gr[h], gsh = gs[h], gch = gc[h];
        int cend = qt * 4 + sc;      // 32-row chunks before this sub-chunk (0..63)
        // contiguous transposed csum: all 64 chunk sums of this (b, col) in flight
        const float4* cs4 = (const float4*)(csum + (size_t)col * 128 + b * 64);
        float run = 0.f;
        #pragma unroll
        for (int g = 0; g < 16; g++) {
            float4 f = cs4[g];
            int j = g * 4;
            run += (j + 0 < cend ? f.x : 0.f) + (j + 1 < cend ? f.y : 0.f)
                 + (j + 2 < cend ? f.z : 0.f) + (j + 3 < cend ? f.w : 0.f);
        }
        const bf16* vrow = vT + (size_t)col * 4096 + b * 2048 + row0;
        U16x8 vv[4];
        #pragma unroll
        for (int g = 0; g < 4; g++) vv[g].u = *(const uint4*)&vrow[g * 8];
        bf16* cp = ctx + ((size_t)(b * S + row0)) * E + col;
        #pragma unroll
        for (int i = 0; i < 32; i++) {
            float v = (float)vv[i >> 3].h[i & 7];
            run += v;
            float pm = run / (float)(row0 + i + 1);
            cp[(size_t)i * E] = (bf16)(grh * (float)osm[sc * 32 + i][c] + gsh * v - gch * pm);
        }
    }
}

extern "C" void kernel_launch(void* const* d_in, const int* in_sizes, int n_in,
                              void* d_out, int out_size, void* d_ws, size_t ws_size,
                              hipStream_t stream) {
    const float* hs  = (const float*)d_in[0];
    const float* qkw = (const float*)d_in[1];
    const float* qkb = (const float*)d_in[2];
    const float* vw  = (const float*)d_in[3];
    const float* vrg = (const float*)d_in[4];
    const float* vsg = (const float*)d_in[5];
    const float* pw  = (const float*)d_in[6];
    const float* prg = (const float*)d_in[7];
    const float* psg = (const float*)d_in[8];
    const float* amr = (const float*)d_in[9];
    const float* ams = (const float*)d_in[10];
    const float* amc = (const float*)d_in[11];
    float* out = (float*)d_out;

    const int B = 2, S = 2048, E = 1024, H = 16, M = B * S;
    char* ws = (char*)d_ws;
    size_t off = 0;
    auto alloc = [&](size_t bytes) { void* p = ws + off; off += (bytes + 255) & ~255ull; return p; };
    bf16* hsb   = (bf16*)alloc((size_t)M * E * 2);
    bf16* qkvT  = (bf16*)alloc((size_t)3 * E * E * 2);
    bf16* pwT   = (bf16*)alloc((size_t)E * E * 2);
    bf16* qko   = (bf16*)alloc((size_t)M * 2 * E * 2);
    bf16* vT    = (bf16*)alloc((size_t)E * M * 2);
    float* csum = (float*)alloc((size_t)E * 128 * 4);   // transposed: [col][chunk32]
    bf16* ctxb  = (bf16*)alloc((size_t)M * E * 2);
    bf16* Opart = (bf16*)alloc((size_t)32 * 40 * 128 * 64 * 2);
    float* lbuf = (float*)alloc((size_t)32 * 40 * 128 * 4);

    prep<<<8200, 256, 0, stream>>>(hs, hsb, qkw, vw, pw, qkvT, pwT, csum, vrg, vsg, prg, psg);

    gemm_bt<128><<<32 * (3 * E / 128), 256, 0, stream>>>(
        hsb, qkvT, M, 3 * E, E, qko, vT, csum, 0, qkb);

    flash_split<<<dim3(40, 32), 256, 0, stream>>>(qko, vT, Opart, lbuf, S, E, H);
    merge_combine<<<dim3(16, 32), 256, 0, stream>>>(Opart, lbuf, vT, csum, amr, ams, amc, ctxb);

    gemm_bt<64><<<32 * (E / 64), 256, 0, stream>>>(
        ctxb, pwT, M, E, E, out, nullptr, nullptr, 2, nullptr);
}